// Round 1
// baseline (47998.468 us; speedup 1.0000x reference)
//
#include <hip/hip_runtime.h>

typedef _Float16 f16;
typedef _Float16 f16x8 __attribute__((ext_vector_type(8)));
typedef float f32x4 __attribute__((ext_vector_type(4)));

// Problem constants
// N=64, T=1024, D=512, H=512, 4H=2048, K_cat = D+H = 1024
//
// ws layout (bytes):
//   x_h   : fp16 x, [64][1024][512]            = 67,108,864  @ 0
//   Wcat  : fp16 [q=2048][k=1024] (q = u*4+g)  =  4,194,304  @ 67,108,864
//   b_p   : fp32 [2048] permuted               =      8,192  @ 71,303,168
//   h_glob: fp16 [2][64][512] ping-pong        =    131,072  @ 71,311,360
//   bar   : u32  [8][32] (one line per group)  =      1,024  @ 71,442,432
#define OFF_WCAT  67108864L
#define OFF_BP    71303168L
#define OFF_HG    71311360L
#define OFF_BAR   71442432L

__global__ void prep_kernel(const float* __restrict__ x, const float* __restrict__ h0,
                            const float* __restrict__ Wx, const float* __restrict__ Wh,
                            const float* __restrict__ b,
                            f16* __restrict__ x_h, f16* __restrict__ Wcat,
                            float* __restrict__ b_p, f16* __restrict__ h_glob,
                            unsigned int* __restrict__ bar)
{
    const int tid = blockIdx.x * blockDim.x + threadIdx.x;   // 4,194,304 threads
    // x -> fp16 (8 elems/thread, coalesced)
    if (tid < 4194304) {
        const float4* src = (const float4*)x;
        float4 a = src[2*tid], c = src[2*tid + 1];
        f16x8 v;
        v[0]=(f16)a.x; v[1]=(f16)a.y; v[2]=(f16)a.z; v[3]=(f16)a.w;
        v[4]=(f16)c.x; v[5]=(f16)c.y; v[6]=(f16)c.z; v[7]=(f16)c.w;
        *(f16x8*)(x_h + (long)tid*8) = v;
    }
    // Wcat[q][k]: q = u*4 + g;  k<512 -> Wx[k][g*512+u], k>=512 -> Wh[k-512][g*512+u]
    if (tid < 2097152) {
        int q = tid >> 10, k = tid & 1023;
        int u = q >> 2, g = q & 3;
        float v = (k < 512) ? Wx[(long)k*2048 + g*512 + u]
                            : Wh[(long)(k-512)*2048 + g*512 + u];
        Wcat[tid] = (f16)v;
    }
    if (tid < 32768) h_glob[tid] = (f16)h0[tid];        // h ping buffer 0
    if (tid < 2048)  b_p[tid] = b[(tid & 3)*512 + (tid >> 2)];
    if (tid < 256)   bar[tid] = 0u;
}

// Persistent recurrence kernel.
// 256 blocks x 256 threads. group g = blk%8 (XCD-affine), wgl = blk/8 in [0,32).
// Group owns batch rows [8g, 8g+8). WG owns hidden units [16*wgl, +16).
// Wave owns 4 units -> 16 gate columns = one 16x16 MFMA N-tile, K=1024.
__global__ __launch_bounds__(256, 1) void lstm_kernel(
    const f16* __restrict__ x_h, const f16* __restrict__ Wcat,
    const float* __restrict__ b_p, f16* __restrict__ h_glob,
    unsigned int* __restrict__ bar, float* __restrict__ out)
{
    constexpr int AS = 536;                 // LDS row stride in halves (16B aligned, bank-spread)
    __shared__ f16 Ax[8 * AS];
    __shared__ f16 Ah[8 * AS];

    const int blk  = blockIdx.x;
    const int g    = blk & 7;
    const int wgl  = blk >> 3;
    const int n0   = g * 8;
    const int tid  = threadIdx.x;
    const int wave = tid >> 6;
    const int lane = tid & 63;
    const int c    = lane & 15;             // tile column
    const int kg   = lane >> 4;             // k-group 0..3
    const int ub   = wgl * 16 + wave * 4;   // first hidden unit of this wave
    const int q0   = ub * 4;                // first gate column (q = u*4 + gate)

    // Load weight B-fragments once; they live in VGPRs for the whole kernel.
    f16x8 wfrag[32];
    {
        const f16* wp = Wcat + (long)(q0 + c) * 1024 + kg * 8;
        #pragma unroll
        for (int kk = 0; kk < 32; ++kk)
            wfrag[kk] = *(const f16x8*)(wp + kk * 32);
    }
    const float bias = b_p[q0 + c];

    const int rowA = lane & 7;              // rows 8..15 duplicate 0..7 (B=8 < Mtile=16)
    const int aoff = rowA * AS + kg * 8;

    float cst[4] = {0.f, 0.f, 0.f, 0.f};    // c-state, 4 row-regs per lane

    const bool do_store = ((lane & 3) == 0) && (lane < 32);
    const int ul = c >> 2;                  // unit-local 0..3
    const int u  = ub + ul;                 // global hidden unit
    const int srcbase = (lane & 48) + (ul << 2);

    unsigned int* mybar = bar + g * 32;
    unsigned int target = 0;
    int cur = 0;

    for (int t = 0; t < 1024; ++t) {
        // ---- stage A = [x_t | h_t] for this group's 8 rows into LDS ----
        {
            const f16* hsrc = h_glob + cur * 32768 + n0 * 512;
            #pragma unroll
            for (int a = tid; a < 512; a += 256) {
                int r = a >> 6, ch = a & 63;
                *(f16x8*)(Ax + r * AS + ch * 8) =
                    *(const f16x8*)(x_h + ((long)(n0 + r) * 1024 + t) * 512 + ch * 8);
                *(f16x8*)(Ah + r * AS + ch * 8) =
                    *(const f16x8*)(hsrc + r * 512 + ch * 8);
            }
        }
        __syncthreads();

        // ---- MFMA: acc = [x|h] @ Wcat_tile, 4 partial accs to break dep chain ----
        f32x4 a0 = {0.f,0.f,0.f,0.f}, a1 = {0.f,0.f,0.f,0.f};
        f32x4 a2 = {0.f,0.f,0.f,0.f}, a3 = {0.f,0.f,0.f,0.f};
        #pragma unroll
        for (int kk = 0; kk < 16; kk += 4) {
            f16x8 f0 = *(const f16x8*)(Ax + aoff + (kk+0) * 32);
            f16x8 f1 = *(const f16x8*)(Ax + aoff + (kk+1) * 32);
            f16x8 f2 = *(const f16x8*)(Ax + aoff + (kk+2) * 32);
            f16x8 f3 = *(const f16x8*)(Ax + aoff + (kk+3) * 32);
            a0 = __builtin_amdgcn_mfma_f32_16x16x32_f16(f0, wfrag[kk+0], a0, 0, 0, 0);
            a1 = __builtin_amdgcn_mfma_f32_16x16x32_f16(f1, wfrag[kk+1], a1, 0, 0, 0);
            a2 = __builtin_amdgcn_mfma_f32_16x16x32_f16(f2, wfrag[kk+2], a2, 0, 0, 0);
            a3 = __builtin_amdgcn_mfma_f32_16x16x32_f16(f3, wfrag[kk+3], a3, 0, 0, 0);
        }
        #pragma unroll
        for (int kk = 0; kk < 16; kk += 4) {
            f16x8 f0 = *(const f16x8*)(Ah + aoff + (kk+0) * 32);
            f16x8 f1 = *(const f16x8*)(Ah + aoff + (kk+1) * 32);
            f16x8 f2 = *(const f16x8*)(Ah + aoff + (kk+2) * 32);
            f16x8 f3 = *(const f16x8*)(Ah + aoff + (kk+3) * 32);
            a0 = __builtin_amdgcn_mfma_f32_16x16x32_f16(f0, wfrag[16+kk+0], a0, 0, 0, 0);
            a1 = __builtin_amdgcn_mfma_f32_16x16x32_f16(f1, wfrag[16+kk+1], a1, 0, 0, 0);
            a2 = __builtin_amdgcn_mfma_f32_16x16x32_f16(f2, wfrag[16+kk+2], a2, 0, 0, 0);
            a3 = __builtin_amdgcn_mfma_f32_16x16x32_f16(f3, wfrag[16+kk+3], a3, 0, 0, 0);
        }

        // ---- epilogue: gather 4 gates of my unit via shfl, LSTM cell update ----
        float hv[4];
        #pragma unroll
        for (int j = 0; j < 4; ++j) {
            float av = ((a0[j] + a1[j]) + (a2[j] + a3[j])) + bias;
            float vi = __shfl(av, srcbase + 0, 64);
            float vf = __shfl(av, srcbase + 1, 64);
            float vo = __shfl(av, srcbase + 2, 64);
            float vg = __shfl(av, srcbase + 3, 64);
            float iv = 1.f / (1.f + __expf(-vi));
            float fv = 1.f / (1.f + __expf(-vf));
            float ov = 1.f / (1.f + __expf(-vo));
            float gv = 2.f / (1.f + __expf(-2.f * vg)) - 1.f;   // tanh
            float cn = fv * cst[j] + iv * gv;
            cst[j] = cn;
            float th = 2.f / (1.f + __expf(-2.f * cn)) - 1.f;   // tanh
            hv[j] = ov * th;
        }

        const int nxt = cur ^ 1;
        if (do_store) {
            #pragma unroll
            for (int j = 0; j < 4; ++j) {
                int row = (lane >> 4) * 4 + j;
                int n = n0 + row;
                h_glob[nxt * 32768 + n * 512 + u] = (f16)hv[j];
                out[((long)n * 1024 + t) * 512 + u] = hv[j];
            }
        }

        // ---- publish + group barrier (agent scope; correct regardless of XCD placement) ----
        __threadfence();                    // release my stores to agent scope
        __syncthreads();                    // whole WG done (stores + LDS reads of this step)
        if (tid == 0)
            __hip_atomic_fetch_add(mybar, 1u, __ATOMIC_RELEASE, __HIP_MEMORY_SCOPE_AGENT);
        target += 32;
        if (tid == 0) {
            while (__hip_atomic_load(mybar, __ATOMIC_ACQUIRE, __HIP_MEMORY_SCOPE_AGENT) < target) {}
        }
        __syncthreads();
        __threadfence();                    // acquire: invalidate stale caches before reading h
        cur = nxt;
    }
}

extern "C" void kernel_launch(void* const* d_in, const int* in_sizes, int n_in,
                              void* d_out, int out_size, void* d_ws, size_t ws_size,
                              hipStream_t stream)
{
    const float* x  = (const float*)d_in[0];
    const float* h0 = (const float*)d_in[1];
    const float* Wx = (const float*)d_in[2];
    const float* Wh = (const float*)d_in[3];
    const float* b  = (const float*)d_in[4];
    float* out = (float*)d_out;

    char* ws = (char*)d_ws;
    f16*   x_h    = (f16*)(ws);
    f16*   Wcat   = (f16*)(ws + OFF_WCAT);
    float* b_p    = (float*)(ws + OFF_BP);
    f16*   h_glob = (f16*)(ws + OFF_HG);
    unsigned int* bar = (unsigned int*)(ws + OFF_BAR);

    prep_kernel<<<16384, 256, 0, stream>>>(x, h0, Wx, Wh, b, x_h, Wcat, b_p, h_glob, bar);
    lstm_kernel<<<256, 256, 0, stream>>>(x_h, Wcat, b_p, h_glob, bar, out);
}

// Round 2
// 5310.597 us; speedup vs baseline: 9.0382x; 9.0382x over previous
//
#include <hip/hip_runtime.h>

typedef _Float16 f16;
typedef _Float16 f16x2 __attribute__((ext_vector_type(2)));
typedef _Float16 f16x8 __attribute__((ext_vector_type(8)));
typedef float f32x4 __attribute__((ext_vector_type(4)));
typedef unsigned long long u64;

// Problem constants: N=64, T=1024, D=512, H=512, 4H=2048, K_cat=1024
//
// ws layout (bytes):
//   x_h   : fp16 x, [64][1024][512]            = 67,108,864  @ 0
//   Wcat  : fp16 [q=2048][k=1024] (q = u*4+g)  =  4,194,304  @ 67,108,864
//   b_p   : fp32 [2048] permuted               =      8,192  @ 71,303,168
//   h_glob: fp32 [2][64][512] ping-pong        =    262,144  @ 71,311,360
//   bar   : u32  [8][32] (one line per group)  =      1,024  @ 71,573,504
#define OFF_WCAT  67108864L
#define OFF_BP    71303168L
#define OFF_HG    71311360L
#define OFF_BAR   71573504L

__global__ void prep_kernel(const float* __restrict__ x, const float* __restrict__ h0,
                            const float* __restrict__ Wx, const float* __restrict__ Wh,
                            const float* __restrict__ b,
                            f16* __restrict__ x_h, f16* __restrict__ Wcat,
                            float* __restrict__ b_p, float* __restrict__ h_glob,
                            unsigned int* __restrict__ bar)
{
    const int tid = blockIdx.x * blockDim.x + threadIdx.x;   // 4,194,304 threads
    if (tid < 4194304) {                                     // x -> fp16, 8/thread
        const float4* src = (const float4*)x;
        float4 a = src[2*tid], c = src[2*tid + 1];
        f16x8 v;
        v[0]=(f16)a.x; v[1]=(f16)a.y; v[2]=(f16)a.z; v[3]=(f16)a.w;
        v[4]=(f16)c.x; v[5]=(f16)c.y; v[6]=(f16)c.z; v[7]=(f16)c.w;
        *(f16x8*)(x_h + (long)tid*8) = v;
    }
    // Wcat[q][k]: q = u*4 + g;  k<512 -> Wx[k][g*512+u], k>=512 -> Wh[k-512][g*512+u]
    if (tid < 2097152) {
        int q = tid >> 10, k = tid & 1023;
        int u = q >> 2, g = q & 3;
        float v = (k < 512) ? Wx[(long)k*2048 + g*512 + u]
                            : Wh[(long)(k-512)*2048 + g*512 + u];
        Wcat[tid] = (f16)v;
    }
    if (tid < 32768) h_glob[tid] = h0[tid];            // h ping buffer 0 (fp32)
    if (tid < 2048)  b_p[tid] = b[(tid & 3)*512 + (tid >> 2)];
    if (tid < 256)   bar[tid] = 0u;
}

// Stage 8 rows x 512 h (fp32, LLC-coherent atomic loads) -> fp16 LDS tile.
__device__ __forceinline__ void stage_Ah(f16* Ah, const float* hbase, int tid, int AS)
{
    const u64* hsrc = (const u64*)hbase;          // 2048 u64 for the 8-row slab
    #pragma unroll
    for (int i = 0; i < 8; ++i) {
        int idx = i * 256 + tid;                  // 0..2047
        u64 v = __hip_atomic_load(hsrc + idx, __ATOMIC_RELAXED, __HIP_MEMORY_SCOPE_AGENT);
        union { u64 u; float f[2]; } cv; cv.u = v;
        f16x2 hh; hh[0] = (f16)cv.f[0]; hh[1] = (f16)cv.f[1];
        int row = idx >> 8, col2 = idx & 255;     // 256 u64 per row
        *(f16x2*)(Ah + row * AS + col2 * 2) = hh;
    }
}

// Persistent recurrence kernel. 256 blocks x 256 threads.
// group g = blk%8, wgl = blk/8 in [0,32). Group owns batch rows [8g,8g+8).
// Wave owns 4 hidden units -> 16 gate columns = one 16x16 MFMA N-tile, K=1024.
// Cross-WG sync: relaxed agent-scope atomics ONLY (sc0/sc1 data path at LLC),
// ordering via explicit s_waitcnt. NO fences (no buffer_wbl2 / buffer_inv).
__global__ __launch_bounds__(256, 1) void lstm_kernel(
    const f16* __restrict__ x_h, const f16* __restrict__ Wcat,
    const float* __restrict__ b_p, float* __restrict__ h_glob,
    unsigned int* __restrict__ bar, float* __restrict__ out)
{
    constexpr int AS = 536;                 // LDS row stride in halves
    __shared__ f16 Ax[8 * AS];
    __shared__ f16 Ah[8 * AS];
    __shared__ float epil[4 * 16 * 20];     // per-wave 16x20 gate transpose scratch

    const int blk  = blockIdx.x;
    const int g    = blk & 7;
    const int wgl  = blk >> 3;
    const int n0   = g * 8;
    const int tid  = threadIdx.x;
    const int wave = tid >> 6;
    const int lane = tid & 63;
    const int c    = lane & 15;             // tile column
    const int kg   = lane >> 4;             // k-group 0..3
    const int ub   = wgl * 16 + wave * 4;   // first hidden unit of this wave
    const int q0   = ub * 4;                // first gate column

    // Weight B-fragments resident in registers for the whole kernel.
    f16x8 wfrag[32];
    {
        const f16* wp = Wcat + (long)(q0 + c) * 1024 + kg * 8;
        #pragma unroll
        for (int kk = 0; kk < 32; ++kk)
            wfrag[kk] = *(const f16x8*)(wp + kk * 32);
    }
    const float bias = b_p[q0 + c];

    const int rowA = lane & 7;
    const int aoff = rowA * AS + kg * 8;
    float* ep = epil + wave * 320;
    const int rb = lane >> 4;

    // Epilogue cell ownership: lanes 0..31, lane = r*4 + ul
    const int er = lane >> 2;               // batch row 0..7
    const int eu = lane & 3;                // unit-local 0..3
    float cst = 0.f;                        // c-state (1 cell per active lane)

    unsigned int* mybar = bar + g * 32;
    int cur = 0;

    // ---- prologue: stage x_0 and h_0 ----
    #pragma unroll
    for (int a = tid; a < 512; a += 256) {
        int r = a >> 6, ch = a & 63;
        *(f16x8*)(Ax + r * AS + ch * 8) =
            *(const f16x8*)(x_h + ((long)(n0 + r) * 1024 + 0) * 512 + ch * 8);
    }
    stage_Ah(Ah, h_glob + n0 * 512, tid, AS);
    __syncthreads();

    for (int t = 0; t < 1024; ++t) {
        // ---- MFMA: acc = [x_t | h_t] @ Wcat_tile ----
        f32x4 a0 = {0.f,0.f,0.f,0.f}, a1 = {0.f,0.f,0.f,0.f};
        f32x4 a2 = {0.f,0.f,0.f,0.f}, a3 = {0.f,0.f,0.f,0.f};
        #pragma unroll
        for (int kk = 0; kk < 16; kk += 4) {
            f16x8 f0 = *(const f16x8*)(Ax + aoff + (kk+0) * 32);
            f16x8 f1 = *(const f16x8*)(Ax + aoff + (kk+1) * 32);
            f16x8 f2 = *(const f16x8*)(Ax + aoff + (kk+2) * 32);
            f16x8 f3 = *(const f16x8*)(Ax + aoff + (kk+3) * 32);
            a0 = __builtin_amdgcn_mfma_f32_16x16x32_f16(f0, wfrag[kk+0], a0, 0, 0, 0);
            a1 = __builtin_amdgcn_mfma_f32_16x16x32_f16(f1, wfrag[kk+1], a1, 0, 0, 0);
            a2 = __builtin_amdgcn_mfma_f32_16x16x32_f16(f2, wfrag[kk+2], a2, 0, 0, 0);
            a3 = __builtin_amdgcn_mfma_f32_16x16x32_f16(f3, wfrag[kk+3], a3, 0, 0, 0);
        }
        #pragma unroll
        for (int kk = 0; kk < 16; kk += 4) {
            f16x8 f0 = *(const f16x8*)(Ah + aoff + (kk+0) * 32);
            f16x8 f1 = *(const f16x8*)(Ah + aoff + (kk+1) * 32);
            f16x8 f2 = *(const f16x8*)(Ah + aoff + (kk+2) * 32);
            f16x8 f3 = *(const f16x8*)(Ah + aoff + (kk+3) * 32);
            a0 = __builtin_amdgcn_mfma_f32_16x16x32_f16(f0, wfrag[16+kk+0], a0, 0, 0, 0);
            a1 = __builtin_amdgcn_mfma_f32_16x16x32_f16(f1, wfrag[16+kk+1], a1, 0, 0, 0);
            a2 = __builtin_amdgcn_mfma_f32_16x16x32_f16(f2, wfrag[16+kk+2], a2, 0, 0, 0);
            a3 = __builtin_amdgcn_mfma_f32_16x16x32_f16(f3, wfrag[16+kk+3], a3, 0, 0, 0);
        }

        // ---- gate transpose via per-wave LDS (same-wave DS is in-order) ----
        #pragma unroll
        for (int j = 0; j < 4; ++j) {
            float av = ((a0[j] + a1[j]) + (a2[j] + a3[j])) + bias;
            ep[(rb * 4 + j) * 20 + c] = av;
        }

        const int nxt = cur ^ 1;
        if (lane < 32) {
            float4 g4 = *(const float4*)(ep + er * 20 + eu * 4);   // i,f,o,g
            float iv = 1.f / (1.f + __expf(-g4.x));
            float fv = 1.f / (1.f + __expf(-g4.y));
            float ov = 1.f / (1.f + __expf(-g4.z));
            float gv = 2.f / (1.f + __expf(-2.f * g4.w)) - 1.f;    // tanh
            float cn = fv * cst + iv * gv;
            cst = cn;
            float th = 2.f / (1.f + __expf(-2.f * cn)) - 1.f;      // tanh
            float hval = ov * th;
            int n = n0 + er;
            int u = ub + eu;
            out[((long)n * 1024 + t) * 512 + u] = hval;
            if (t < 1023)
                __hip_atomic_store(h_glob + nxt * 32768 + n * 512 + u, hval,
                                   __ATOMIC_RELAXED, __HIP_MEMORY_SCOPE_AGENT);
        }

        if (t < 1023) {
            // ---- release: drain my stores to LLC, then per-wave arrive ----
            __builtin_amdgcn_s_waitcnt(0);
            if (lane == 0)
                __hip_atomic_fetch_add(mybar, 1u, __ATOMIC_RELAXED, __HIP_MEMORY_SCOPE_AGENT);
            __syncthreads();                 // all waves arrived; Ax/Ah reads done

            // ---- restage x_{t+1} (hidden under the spin window) ----
            #pragma unroll
            for (int a = tid; a < 512; a += 256) {
                int r = a >> 6, ch = a & 63;
                *(f16x8*)(Ax + r * AS + ch * 8) =
                    *(const f16x8*)(x_h + ((long)(n0 + r) * 1024 + (t+1)) * 512 + ch * 8);
            }

            // ---- acquire: spin on group counter (relaxed; sc1 reads LLC) ----
            if (tid == 0) {
                unsigned int tgt = 128u * (unsigned)(t + 1);
                while (__hip_atomic_load(mybar, __ATOMIC_RELAXED, __HIP_MEMORY_SCOPE_AGENT) < tgt) {}
            }
            __syncthreads();
            __asm__ volatile("" ::: "memory");

            // ---- stage h_{t+1} ----
            stage_Ah(Ah, h_glob + nxt * 32768 + n0 * 512, tid, AS);
            __syncthreads();
            cur = nxt;
        }
    }
}

extern "C" void kernel_launch(void* const* d_in, const int* in_sizes, int n_in,
                              void* d_out, int out_size, void* d_ws, size_t ws_size,
                              hipStream_t stream)
{
    const float* x  = (const float*)d_in[0];
    const float* h0 = (const float*)d_in[1];
    const float* Wx = (const float*)d_in[2];
    const float* Wh = (const float*)d_in[3];
    const float* b  = (const float*)d_in[4];
    float* out = (float*)d_out;

    char* ws = (char*)d_ws;
    f16*   x_h    = (f16*)(ws);
    f16*   Wcat   = (f16*)(ws + OFF_WCAT);
    float* b_p    = (float*)(ws + OFF_BP);
    float* h_glob = (float*)(ws + OFF_HG);
    unsigned int* bar = (unsigned int*)(ws + OFF_BAR);

    prep_kernel<<<16384, 256, 0, stream>>>(x, h0, Wx, Wh, b, x_h, Wcat, b_p, h_glob, bar);
    lstm_kernel<<<256, 256, 0, stream>>>(x_h, Wcat, b_p, h_glob, bar, out);
}